// Round 1
// baseline (355.224 us; speedup 1.0000x reference)
//
#include <hip/hip_runtime.h>

typedef _Float16 half8   __attribute__((ext_vector_type(8)));
typedef _Float16 half4_t __attribute__((ext_vector_type(4)));
typedef float    float4_t __attribute__((ext_vector_type(4)));

#define B_   8
#define N_   4096
#define C_   256
#define F_   64

static __device__ __forceinline__ float4_t mfma16(half8 a, half8 b, float4_t c) {
  return __builtin_amdgcn_mfma_f32_16x16x32_f16(a, b, c, 0, 0, 0);
}

// ---------------- prep: WhvT[d][c] = sum_e Wh[c][e]*Wv[e][d], f16 ----------------
__global__ __launch_bounds__(256) void prep_whvt(const float* __restrict__ Wh,
                                                 const float* __restrict__ Wv,
                                                 _Float16* __restrict__ whvt) {
  int d = blockIdx.x;    // 0..255
  int c = threadIdx.x;   // 0..255
  float acc = 0.f;
  for (int e = 0; e < 256; ++e)
    acc += Wh[c * 256 + e] * Wv[e * 256 + d];
  whvt[d * 256 + c] = (_Float16)acc;   // coalesced write
}

// ---------------- prep: wfgt[n][c] = (n<64 ? Wf[c][n] : Wg[c][n-64]), f16 --------
__global__ __launch_bounds__(256) void prep_wfgt(const float* __restrict__ Wf,
                                                 const float* __restrict__ Wg,
                                                 _Float16* __restrict__ wfgt) {
  int n = blockIdx.x;    // 0..127
  int c = threadIdx.x;   // 0..255
  float v = (n < 64) ? Wf[c * 64 + n] : Wg[c * 64 + (n - 64)];
  wfgt[n * 256 + c] = (_Float16)v;
}

// ---------------- prep: xT[b][c][n] = (f16)x[b][n][c] ----------------------------
__global__ __launch_bounds__(256) void transpose_x(const float* __restrict__ x,
                                                   _Float16* __restrict__ xT) {
  __shared__ float tile[32][33];
  int b  = blockIdx.x >> 7;
  int n0 = (blockIdx.x & 127) << 5;
  int c0 = blockIdx.y << 5;
  int tid = threadIdx.x;
  int r  = tid >> 3;          // 0..31
  int cc = (tid & 7) << 2;    // 0,4,..,28
  const float* src = x + ((size_t)(b * N_ + n0 + r)) * C_ + c0 + cc;
  float4_t v = *(const float4_t*)src;
  tile[r][cc + 0] = v[0]; tile[r][cc + 1] = v[1];
  tile[r][cc + 2] = v[2]; tile[r][cc + 3] = v[3];
  __syncthreads();
  half4_t o;
  o[0] = (_Float16)tile[cc + 0][r];
  o[1] = (_Float16)tile[cc + 1][r];
  o[2] = (_Float16)tile[cc + 2][r];
  o[3] = (_Float16)tile[cc + 3][r];
  _Float16* dst = xT + ((size_t)(b * C_ + c0 + r)) * N_ + n0 + cc;
  *(half4_t*)dst = o;
}

// ---------------- f,g GEMM: [32768x256] @ wfgt^T -> f16 [32768x64] x2 ------------
__global__ __launch_bounds__(256) void fg_kernel(const float* __restrict__ x,
                                                 const _Float16* __restrict__ wfgt,
                                                 _Float16* __restrict__ f,
                                                 _Float16* __restrict__ g) {
  int tid  = threadIdx.x;
  int wave = tid >> 6, lane = tid & 63;
  int n16  = lane & 15, quad = lane >> 4;
  int row  = blockIdx.x * 64 + wave * 16 + n16;   // A m-index
  float4_t acc[8];
#pragma unroll
  for (int t = 0; t < 8; t++) acc[t] = (float4_t){0.f, 0.f, 0.f, 0.f};
  for (int k0 = 0; k0 < 256; k0 += 32) {
    const float* xp = x + (size_t)row * C_ + k0 + quad * 8;
    float4_t x0 = *(const float4_t*)xp;
    float4_t x1 = *(const float4_t*)(xp + 4);
    half8 af;
#pragma unroll
    for (int j = 0; j < 4; j++) { af[j] = (_Float16)x0[j]; af[4 + j] = (_Float16)x1[j]; }
#pragma unroll
    for (int t = 0; t < 8; t++) {
      half8 bf = *(const half8*)(wfgt + (size_t)(t * 16 + n16) * 256 + k0 + quad * 8);
      acc[t] = mfma16(af, bf, acc[t]);
    }
  }
  int orow = blockIdx.x * 64 + wave * 16 + quad * 4;  // D row = quad*4+reg
#pragma unroll
  for (int t = 0; t < 8; t++) {
#pragma unroll
    for (int r = 0; r < 4; r++) {
      _Float16 v = (_Float16)acc[t][r];
      int col = t * 16 + n16;
      if (t < 4) f[(size_t)(orow + r) * 64 + col] = v;
      else       g[(size_t)(orow + r) * 64 + col - 64] = v;
    }
  }
}

// ---------------- flash attention: a = softmax(f g^T) @ x  (f16 in, f16 out) -----
#define KT_LD 72
#define VT_LD 72
#define PT_LD 72

__global__ __launch_bounds__(256, 2) void flash_kernel(const _Float16* __restrict__ f,
                                                       const _Float16* __restrict__ g,
                                                       const _Float16* __restrict__ xT,
                                                       _Float16* __restrict__ a) {
  __shared__ _Float16 kt[64 * KT_LD];        // K tile [j][k]
  __shared__ _Float16 vt[256 * VT_LD];       // V tile [c][j] (x transposed)
  __shared__ _Float16 pt[4][16 * PT_LD];     // per-wave P tile [i][j]

  const int b   = blockIdx.x;
  const int i0  = blockIdx.y * 64;
  const int tid = threadIdx.x;
  const int wave = tid >> 6, lane = tid & 63;
  const int n16 = lane & 15, quad = lane >> 4;
  const int row_base = b * N_ + i0 + wave * 16;

  // Q fragments in registers (K=64 -> 2 k-steps), A-layout: m=lane&15, k=quad*8+j
  half8 qf[2];
  {
    const _Float16* qp = f + (size_t)(row_base + n16) * 64 + quad * 8;
    qf[0] = *(const half8*)qp;
    qf[1] = *(const half8*)(qp + 32);
  }

  float4_t o_acc[16];
#pragma unroll
  for (int t = 0; t < 16; t++) o_acc[t] = (float4_t){0.f, 0.f, 0.f, 0.f};
  float m_i[4] = {-1e30f, -1e30f, -1e30f, -1e30f};
  float l_i[4] = {0.f, 0.f, 0.f, 0.f};

  const int kjr  = tid >> 2;            // K-tile staging: row 0..63
  const int kseg = (tid & 3) * 16;      // 32B per thread x2
  const int vc0  = tid >> 3;            // V-tile staging: c row 0..31 (+32*u)
  const int vo   = (tid & 7) * 8;       // 16B per thread
  const _Float16* gbase = g + (size_t)(b * N_) * 64;
  const _Float16* xbase = xT + (size_t)b * C_ * N_;

  for (int j0 = 0; j0 < N_; j0 += 64) {
    // stage K tile (64x64)
    {
      const _Float16* src = gbase + (size_t)(j0 + kjr) * 64 + kseg;
      _Float16* dst = kt + kjr * KT_LD + kseg;
      *(half8*)dst       = *(const half8*)src;
      *(half8*)(dst + 8) = *(const half8*)(src + 8);
    }
    // stage V tile (256x64), coalesced in j
#pragma unroll
    for (int u = 0; u < 8; ++u) {
      int c = vc0 + u * 32;
      const _Float16* src = xbase + (size_t)c * N_ + j0 + vo;
      *(half8*)(vt + c * VT_LD + vo) = *(const half8*)src;
    }
    __syncthreads();

    // S = Q K^T  (16 rows x 64 cols per wave)
    float4_t s_acc[4];
#pragma unroll
    for (int t = 0; t < 4; t++) s_acc[t] = (float4_t){0.f, 0.f, 0.f, 0.f};
#pragma unroll
    for (int s = 0; s < 2; s++) {
#pragma unroll
      for (int t = 0; t < 4; t++) {
        half8 bf = *(const half8*)(kt + (t * 16 + n16) * KT_LD + s * 32 + quad * 8);
        s_acc[t] = mfma16(qf[s], bf, s_acc[t]);
      }
    }

    // online softmax (rows r = quad*4+r live in the quad's 16 lanes)
    float alpha[4];
#pragma unroll
    for (int r = 0; r < 4; r++) {
      float v = fmaxf(fmaxf(s_acc[0][r], s_acc[1][r]),
                      fmaxf(s_acc[2][r], s_acc[3][r]));
#pragma unroll
      for (int d = 1; d < 16; d <<= 1)
        v = fmaxf(v, __shfl_xor(v, d, 16));
      float mn = fmaxf(m_i[r], v);
      alpha[r] = __expf(m_i[r] - mn);
      m_i[r] = mn;
    }
    _Float16* pw = &pt[wave][0];
#pragma unroll
    for (int r = 0; r < 4; r++) {
      float s0 = __expf(s_acc[0][r] - m_i[r]);
      float s1 = __expf(s_acc[1][r] - m_i[r]);
      float s2 = __expf(s_acc[2][r] - m_i[r]);
      float s3 = __expf(s_acc[3][r] - m_i[r]);
      float v = s0 + s1 + s2 + s3;
#pragma unroll
      for (int d = 1; d < 16; d <<= 1)
        v += __shfl_xor(v, d, 16);
      l_i[r] = l_i[r] * alpha[r] + v;
      int prow = (quad * 4 + r) * PT_LD + n16;
      pw[prow]      = (_Float16)s0;
      pw[prow + 16] = (_Float16)s1;
      pw[prow + 32] = (_Float16)s2;
      pw[prow + 48] = (_Float16)s3;
    }
    // rescale O accumulator
#pragma unroll
    for (int t = 0; t < 16; t++) {
      o_acc[t][0] *= alpha[0]; o_acc[t][1] *= alpha[1];
      o_acc[t][2] *= alpha[2]; o_acc[t][3] *= alpha[3];
    }
    asm volatile("s_waitcnt lgkmcnt(0)" ::: "memory");  // P writes visible to own wave
    // O += P V   (P in A-layout from LDS, V^T tiles as B)
#pragma unroll
    for (int s = 0; s < 2; s++) {
      half8 af = *(const half8*)(pw + n16 * PT_LD + s * 32 + quad * 8);
#pragma unroll
      for (int t = 0; t < 16; t++) {
        half8 bf = *(const half8*)(vt + (t * 16 + n16) * VT_LD + s * 32 + quad * 8);
        o_acc[t] = mfma16(af, bf, o_acc[t]);
      }
    }
    __syncthreads();
  }

  // epilogue: a = O / l  (f16)
  float inv_l[4];
#pragma unroll
  for (int r = 0; r < 4; r++) inv_l[r] = 1.f / l_i[r];
  const size_t arow0 = (size_t)(row_base + quad * 4) * C_;
#pragma unroll
  for (int t = 0; t < 16; t++) {
#pragma unroll
    for (int r = 0; r < 4; r++)
      a[arow0 + (size_t)r * C_ + t * 16 + n16] = (_Float16)(o_acc[t][r] * inv_l[r]);
  }
}

// ---------------- epilogue GEMM: out = gamma * (a @ Whv) + x ---------------------
__global__ __launch_bounds__(256) void out_kernel(const _Float16* __restrict__ a,
                                                  const _Float16* __restrict__ whvt,
                                                  const float* __restrict__ x,
                                                  const float* __restrict__ gamma,
                                                  float* __restrict__ out) {
  int tid  = threadIdx.x;
  int wave = tid >> 6, lane = tid & 63;
  int n16  = lane & 15, quad = lane >> 4;
  int row  = blockIdx.x * 64 + wave * 16 + n16;
  float4_t acc[16];
#pragma unroll
  for (int t = 0; t < 16; t++) acc[t] = (float4_t){0.f, 0.f, 0.f, 0.f};
  for (int k0 = 0; k0 < 256; k0 += 32) {
    half8 af = *(const half8*)(a + (size_t)row * C_ + k0 + quad * 8);
#pragma unroll
    for (int t = 0; t < 16; t++) {
      half8 bf = *(const half8*)(whvt + (size_t)(t * 16 + n16) * 256 + k0 + quad * 8);
      acc[t] = mfma16(af, bf, acc[t]);
    }
  }
  float gm = gamma[0];
  int orow = blockIdx.x * 64 + wave * 16 + quad * 4;
#pragma unroll
  for (int t = 0; t < 16; t++) {
#pragma unroll
    for (int r = 0; r < 4; r++) {
      size_t idx = (size_t)(orow + r) * C_ + t * 16 + n16;
      out[idx] = gm * acc[t][r] + x[idx];
    }
  }
}

extern "C" void kernel_launch(void* const* d_in, const int* in_sizes, int n_in,
                              void* d_out, int out_size, void* d_ws, size_t ws_size,
                              hipStream_t stream) {
  const float* x     = (const float*)d_in[0];
  const float* Wf    = (const float*)d_in[1];
  const float* Wg    = (const float*)d_in[2];
  const float* Wh    = (const float*)d_in[3];
  const float* Wv    = (const float*)d_in[4];
  const float* gamma = (const float*)d_in[5];
  float* out = (float*)d_out;

  // workspace layout (f16 buffers), total ~40.2 MiB
  char* w = (char*)d_ws;
  _Float16* whvt = (_Float16*)(w);                                  // 256*256*2   = 128 KiB
  _Float16* wfgt = (_Float16*)(w + 131072);                         // 128*256*2   =  64 KiB
  _Float16* fb   = (_Float16*)(w + 196608);                         // 32768*64*2  =   4 MiB
  _Float16* gb   = (_Float16*)(w + 196608 + 4194304);               // 32768*64*2  =   4 MiB
  _Float16* xT   = (_Float16*)(w + 196608 + 2 * 4194304);           // 8*256*4096*2= 16 MiB
  _Float16* ab   = (_Float16*)(w + 196608 + 2 * 4194304 + 16777216);// 32768*256*2 = 16 MiB

  hipLaunchKernelGGL(prep_whvt,  dim3(256),     dim3(256), 0, stream, Wh, Wv, whvt);
  hipLaunchKernelGGL(prep_wfgt,  dim3(128),     dim3(256), 0, stream, Wf, Wg, wfgt);
  hipLaunchKernelGGL(transpose_x,dim3(1024, 8), dim3(256), 0, stream, x, xT);
  hipLaunchKernelGGL(fg_kernel,  dim3(512),     dim3(256), 0, stream, x, wfgt, fb, gb);
  hipLaunchKernelGGL(flash_kernel, dim3(8, 64), dim3(256), 0, stream, fb, gb, xT, ab);
  hipLaunchKernelGGL(out_kernel, dim3(512),     dim3(256), 0, stream, ab, whvt, x, gamma, out);
}

// Round 2
// 293.178 us; speedup vs baseline: 1.2116x; 1.2116x over previous
//
#include <hip/hip_runtime.h>

typedef _Float16 half8   __attribute__((ext_vector_type(8)));
typedef _Float16 half4_t __attribute__((ext_vector_type(4)));
typedef float    float4_t __attribute__((ext_vector_type(4)));

#define B_   8
#define N_   4096
#define C_   256
#define F_   64

static __device__ __forceinline__ float4_t mfma16(half8 a, half8 b, float4_t c) {
  return __builtin_amdgcn_mfma_f32_16x16x32_f16(a, b, c, 0, 0, 0);
}

// ---------------- prep: WhvT[d][c] = sum_e Wh[c][e]*Wv[e][d], f16 ----------------
__global__ __launch_bounds__(256) void prep_whvt(const float* __restrict__ Wh,
                                                 const float* __restrict__ Wv,
                                                 _Float16* __restrict__ whvt) {
  int d = blockIdx.x;    // 0..255 (uniform per block -> Wv reads become s_loads)
  int c = threadIdx.x;   // 0..255
  const float4_t* whr = (const float4_t*)(Wh + (size_t)c * 256);
  float acc = 0.f;
#pragma unroll 8
  for (int e4 = 0; e4 < 64; ++e4) {
    float4_t w4 = whr[e4];
    acc += w4[0] * Wv[(e4 * 4 + 0) * 256 + d];
    acc += w4[1] * Wv[(e4 * 4 + 1) * 256 + d];
    acc += w4[2] * Wv[(e4 * 4 + 2) * 256 + d];
    acc += w4[3] * Wv[(e4 * 4 + 3) * 256 + d];
  }
  whvt[d * 256 + c] = (_Float16)acc;
}

// ---------------- prep: wfgt[n][c] = (n<64 ? Wf[c][n] : Wg[c][n-64]), f16 --------
__global__ __launch_bounds__(256) void prep_wfgt(const float* __restrict__ Wf,
                                                 const float* __restrict__ Wg,
                                                 _Float16* __restrict__ wfgt) {
  int n = blockIdx.x;    // 0..127
  int c = threadIdx.x;   // 0..255
  float v = (n < 64) ? Wf[c * 64 + n] : Wg[c * 64 + (n - 64)];
  wfgt[n * 256 + c] = (_Float16)v;
}

// ---------------- prep: xT[b][c][n] = (f16)x[b][n][c] ----------------------------
__global__ __launch_bounds__(256) void transpose_x(const float* __restrict__ x,
                                                   _Float16* __restrict__ xT) {
  __shared__ float tile[32][33];
  int b  = blockIdx.x >> 7;
  int n0 = (blockIdx.x & 127) << 5;
  int c0 = blockIdx.y << 5;
  int tid = threadIdx.x;
  int r  = tid >> 3;          // 0..31
  int cc = (tid & 7) << 2;    // 0,4,..,28
  const float* src = x + ((size_t)(b * N_ + n0 + r)) * C_ + c0 + cc;
  float4_t v = *(const float4_t*)src;
  tile[r][cc + 0] = v[0]; tile[r][cc + 1] = v[1];
  tile[r][cc + 2] = v[2]; tile[r][cc + 3] = v[3];
  __syncthreads();
  half4_t o;
  o[0] = (_Float16)tile[cc + 0][r];
  o[1] = (_Float16)tile[cc + 1][r];
  o[2] = (_Float16)tile[cc + 2][r];
  o[3] = (_Float16)tile[cc + 3][r];
  _Float16* dst = xT + ((size_t)(b * C_ + c0 + r)) * N_ + n0 + cc;
  *(half4_t*)dst = o;
}

// ---------------- f,g GEMM: [32768x256] @ wfgt^T -> f16 [32768x64] x2 ------------
__global__ __launch_bounds__(256) void fg_kernel(const float* __restrict__ x,
                                                 const _Float16* __restrict__ wfgt,
                                                 _Float16* __restrict__ f,
                                                 _Float16* __restrict__ g) {
  int tid  = threadIdx.x;
  int wave = tid >> 6, lane = tid & 63;
  int n16  = lane & 15, quad = lane >> 4;
  int row  = blockIdx.x * 64 + wave * 16 + n16;   // A m-index
  float4_t acc[8];
#pragma unroll
  for (int t = 0; t < 8; t++) acc[t] = (float4_t){0.f, 0.f, 0.f, 0.f};
  for (int k0 = 0; k0 < 256; k0 += 32) {
    const float* xp = x + (size_t)row * C_ + k0 + quad * 8;
    float4_t x0 = *(const float4_t*)xp;
    float4_t x1 = *(const float4_t*)(xp + 4);
    half8 af;
#pragma unroll
    for (int j = 0; j < 4; j++) { af[j] = (_Float16)x0[j]; af[4 + j] = (_Float16)x1[j]; }
#pragma unroll
    for (int t = 0; t < 8; t++) {
      half8 bf = *(const half8*)(wfgt + (size_t)(t * 16 + n16) * 256 + k0 + quad * 8);
      acc[t] = mfma16(af, bf, acc[t]);
    }
  }
  int orow = blockIdx.x * 64 + wave * 16 + quad * 4;  // D row = quad*4+reg
#pragma unroll
  for (int t = 0; t < 8; t++) {
#pragma unroll
    for (int r = 0; r < 4; r++) {
      _Float16 v = (_Float16)acc[t][r];
      int col = t * 16 + n16;
      if (t < 4) f[(size_t)(orow + r) * 64 + col] = v;
      else       g[(size_t)(orow + r) * 64 + col - 64] = v;
    }
  }
}

// ---------------- flash attention (C-split): a = softmax(f g^T) @ x --------------
// Block: 4 waves, 64 Q-rows. Wave w owns Q-rows [16w,16w+16) for S/softmax and
// O-channels [64w, 64w+64) for PV. P tile (64x64) + softmax alpha shared via
// double-buffered LDS; K tile double-buffered in LDS (prefetched 1 iter ahead);
// V fragments read straight from L2-resident xT. XOR-swizzle (k>>3)^(row&7) on
// kt/pt rows makes every quarter-wave b128 access cover all 8 bank windows 2x.
__global__ __launch_bounds__(256, 2) void flash_kernel(const _Float16* __restrict__ f,
                                                       const _Float16* __restrict__ g,
                                                       const _Float16* __restrict__ xT,
                                                       _Float16* __restrict__ a) {
  __shared__ _Float16 ktb2[2][64 * 64];   // K tile, swizzled
  __shared__ _Float16 ptb2[2][64 * 64];   // P tile, swizzled
  __shared__ float alpha_lds[2][64];
  __shared__ float linv_lds[64];

  const int b   = blockIdx.x;
  const int i0  = blockIdx.y * 64;
  const int tid = threadIdx.x;
  const int wave = tid >> 6, lane = tid & 63;
  const int n16 = lane & 15, quad = lane >> 4;
  const int nlo = n16 & 7, nhi = n16 >> 3;

  // Q fragments (A-layout: m=n16, k=quad*8+j), rows 16w..16w+15 of this i-tile
  half8 qf[2];
  {
    const _Float16* qp = f + (size_t)(b * N_ + i0 + wave * 16 + n16) * 64 + quad * 8;
    qf[0] = *(const half8*)qp;
    qf[1] = *(const half8*)(qp + 32);
  }

  float4_t o_acc[16];   // [ti*4+ct]: rows ti*16+4q+r, cols 64w+16ct+n16
#pragma unroll
  for (int t = 0; t < 16; t++) o_acc[t] = (float4_t){0.f, 0.f, 0.f, 0.f};
  float m_i[4] = {-1e30f, -1e30f, -1e30f, -1e30f};
  float l_i[4] = {0.f, 0.f, 0.f, 0.f};

  const _Float16* gbase = g + (size_t)(b * N_) * 64;
  const _Float16* xbase = xT + ((size_t)b * C_ + 64 * wave) * (size_t)N_;

  // K staging geometry: thread covers row krow, col blocks kcb, kcb+1
  const int krow = tid >> 2;
  const int kcb  = (tid & 3) << 1;
  const int krb  = krow & 7;

  // stage K tile for j0=0
  {
    const _Float16* ks = gbase + (size_t)krow * 64 + (kcb << 3);
    half8 k0 = *(const half8*)ks;
    half8 k1 = *(const half8*)(ks + 8);
    _Float16* kd = ktb2[0] + krow * 64;
    *(half8*)(kd + (((kcb    ) ^ krb) << 3)) = k0;
    *(half8*)(kd + (((kcb + 1) ^ krb) << 3)) = k1;
  }
  __syncthreads();

  for (int k = 0; k < 64; ++k) {
    const int j0  = k << 6;
    const int buf = k & 1;
    const int j0n = (j0 + 64) & (N_ - 1);

    // prefetch next K tile into regs
    half8 kp0, kp1;
    {
      const _Float16* ks = gbase + (size_t)(j0n + krow) * 64 + (kcb << 3);
      kp0 = *(const half8*)ks;
      kp1 = *(const half8*)(ks + 8);
    }
    // V fragments for this iter straight from global (L2)
    half8 vfr[8];
#pragma unroll
    for (int s = 0; s < 2; s++)
#pragma unroll
      for (int ct = 0; ct < 4; ct++)
        vfr[s * 4 + ct] = *(const half8*)(xbase + (size_t)(16 * ct + n16) * N_ +
                                          j0 + 32 * s + 8 * quad);

    // S = Q K^T for this wave's 16 rows
    float4_t s_acc[4];
#pragma unroll
    for (int t = 0; t < 4; t++) s_acc[t] = (float4_t){0.f, 0.f, 0.f, 0.f};
    {
      const _Float16* ktb = ktb2[buf];
#pragma unroll
      for (int s = 0; s < 2; s++)
#pragma unroll
        for (int t = 0; t < 4; t++) {
          half8 bf = *(const half8*)(ktb + (16 * t + n16) * 64 +
                                     (((4 * s + quad) ^ nlo) << 3));
          s_acc[t] = mfma16(qf[s], bf, s_acc[t]);
        }
    }

    // online softmax for this wave's rows; write P (swizzled) + alpha to LDS
    float alpha_r[4];
#pragma unroll
    for (int r = 0; r < 4; r++) {
      float v = fmaxf(fmaxf(s_acc[0][r], s_acc[1][r]),
                      fmaxf(s_acc[2][r], s_acc[3][r]));
#pragma unroll
      for (int d = 1; d < 16; d <<= 1)
        v = fmaxf(v, __shfl_xor(v, d, 16));
      float mn = fmaxf(m_i[r], v);
      alpha_r[r] = __expf(m_i[r] - mn);
      m_i[r] = mn;
    }
    _Float16* pb = ptb2[buf];
#pragma unroll
    for (int r = 0; r < 4; r++) {
      float s0 = __expf(s_acc[0][r] - m_i[r]);
      float s1 = __expf(s_acc[1][r] - m_i[r]);
      float s2 = __expf(s_acc[2][r] - m_i[r]);
      float s3 = __expf(s_acc[3][r] - m_i[r]);
      float v = s0 + s1 + s2 + s3;
#pragma unroll
      for (int d = 1; d < 16; d <<= 1)
        v += __shfl_xor(v, d, 16);
      l_i[r] = l_i[r] * alpha_r[r] + v;
      const int row = wave * 16 + 4 * quad + r;
      const int rb  = row & 7;
      _Float16* pr = pb + row * 64 + nlo;
      pr[((nhi    ) ^ rb) << 3] = (_Float16)s0;
      pr[((nhi + 2) ^ rb) << 3] = (_Float16)s1;
      pr[((nhi + 4) ^ rb) << 3] = (_Float16)s2;
      pr[((nhi + 6) ^ rb) << 3] = (_Float16)s3;
    }
    if (n16 == 0) {
#pragma unroll
      for (int r = 0; r < 4; r++)
        alpha_lds[buf][wave * 16 + 4 * quad + r] = alpha_r[r];
    }
    // write prefetched K tile into other buffer
    {
      _Float16* kd = ktb2[buf ^ 1] + krow * 64;
      *(half8*)(kd + (((kcb    ) ^ krb) << 3)) = kp0;
      *(half8*)(kd + (((kcb + 1) ^ krb) << 3)) = kp1;
    }
    __syncthreads();

    // rescale O by alpha of each row (broadcast LDS reads)
#pragma unroll
    for (int ti = 0; ti < 4; ti++)
#pragma unroll
      for (int r = 0; r < 4; r++) {
        float al = alpha_lds[buf][ti * 16 + 4 * quad + r];
#pragma unroll
        for (int ct = 0; ct < 4; ct++) o_acc[ti * 4 + ct][r] *= al;
      }

    // O += P V  (P from shared LDS, V from regs)
#pragma unroll
    for (int s = 0; s < 2; s++)
#pragma unroll
      for (int ti = 0; ti < 4; ti++) {
        half8 af = *(const half8*)(pb + (16 * ti + n16) * 64 +
                                   (((4 * s + quad) ^ nlo) << 3));
#pragma unroll
        for (int ct = 0; ct < 4; ct++)
          o_acc[ti * 4 + ct] = mfma16(af, vfr[s * 4 + ct], o_acc[ti * 4 + ct]);
      }
  }

  // share 1/l across waves, then write out a = O / l
  if (n16 == 0) {
#pragma unroll
    for (int r = 0; r < 4; r++)
      linv_lds[wave * 16 + 4 * quad + r] = 1.f / l_i[r];
  }
  __syncthreads();
#pragma unroll
  for (int ti = 0; ti < 4; ti++)
#pragma unroll
    for (int r = 0; r < 4; r++) {
      float il = linv_lds[ti * 16 + 4 * quad + r];
      size_t orow = (size_t)(b * N_ + i0 + ti * 16 + 4 * quad + r) * C_;
#pragma unroll
      for (int ct = 0; ct < 4; ct++)
        a[orow + 64 * wave + 16 * ct + n16] =
            (_Float16)(o_acc[ti * 4 + ct][r] * il);
    }
}

// ---------------- epilogue GEMM: out = gamma * (a @ Whv) + x ---------------------
__global__ __launch_bounds__(256) void out_kernel(const _Float16* __restrict__ a,
                                                  const _Float16* __restrict__ whvt,
                                                  const float* __restrict__ x,
                                                  const float* __restrict__ gamma,
                                                  float* __restrict__ out) {
  int tid  = threadIdx.x;
  int wave = tid >> 6, lane = tid & 63;
  int n16  = lane & 15, quad = lane >> 4;
  int row  = blockIdx.x * 64 + wave * 16 + n16;
  float4_t acc[16];
#pragma unroll
  for (int t = 0; t < 16; t++) acc[t] = (float4_t){0.f, 0.f, 0.f, 0.f};
  for (int k0 = 0; k0 < 256; k0 += 32) {
    half8 af = *(const half8*)(a + (size_t)row * C_ + k0 + quad * 8);
#pragma unroll
    for (int t = 0; t < 16; t++) {
      half8 bf = *(const half8*)(whvt + (size_t)(t * 16 + n16) * 256 + k0 + quad * 8);
      acc[t] = mfma16(af, bf, acc[t]);
    }
  }
  float gm = gamma[0];
  int orow = blockIdx.x * 64 + wave * 16 + quad * 4;
#pragma unroll
  for (int t = 0; t < 16; t++) {
#pragma unroll
    for (int r = 0; r < 4; r++) {
      size_t idx = (size_t)(orow + r) * C_ + t * 16 + n16;
      out[idx] = gm * acc[t][r] + x[idx];
    }
  }
}

extern "C" void kernel_launch(void* const* d_in, const int* in_sizes, int n_in,
                              void* d_out, int out_size, void* d_ws, size_t ws_size,
                              hipStream_t stream) {
  const float* x     = (const float*)d_in[0];
  const float* Wf    = (const float*)d_in[1];
  const float* Wg    = (const float*)d_in[2];
  const float* Wh    = (const float*)d_in[3];
  const float* Wv    = (const float*)d_in[4];
  const float* gamma = (const float*)d_in[5];
  float* out = (float*)d_out;

  char* w = (char*)d_ws;
  _Float16* whvt = (_Float16*)(w);                                  // 128 KiB
  _Float16* wfgt = (_Float16*)(w + 131072);                         //  64 KiB
  _Float16* fb   = (_Float16*)(w + 196608);                         //   4 MiB
  _Float16* gb   = (_Float16*)(w + 196608 + 4194304);               //   4 MiB
  _Float16* xT   = (_Float16*)(w + 196608 + 2 * 4194304);           //  16 MiB
  _Float16* ab   = (_Float16*)(w + 196608 + 2 * 4194304 + 16777216);//  16 MiB

  hipLaunchKernelGGL(prep_whvt,  dim3(256),     dim3(256), 0, stream, Wh, Wv, whvt);
  hipLaunchKernelGGL(prep_wfgt,  dim3(128),     dim3(256), 0, stream, Wf, Wg, wfgt);
  hipLaunchKernelGGL(transpose_x,dim3(1024, 8), dim3(256), 0, stream, x, xT);
  hipLaunchKernelGGL(fg_kernel,  dim3(512),     dim3(256), 0, stream, x, wfgt, fb, gb);
  hipLaunchKernelGGL(flash_kernel, dim3(8, 64), dim3(256), 0, stream, fb, gb, xT, ab);
  hipLaunchKernelGGL(out_kernel, dim3(512),     dim3(256), 0, stream, ab, whvt, x, gamma, out);
}